// Round 1
// baseline (488.687 us; speedup 1.0000x reference)
//
#include <hip/hip_runtime.h>
#include <hip/hip_bf16.h>
#include <math.h>

#define TSEQ 4096
#define CDIM 768
#define NH 12
#define HD 64

typedef float f32x4 __attribute__((ext_vector_type(4)));
typedef __bf16 bf16x8 __attribute__((ext_vector_type(8)));
typedef short s16x8 __attribute__((ext_vector_type(8)));

__device__ inline ushort f2bf(float f) {
  __hip_bfloat16 h = __float2bfloat16(f);
  return __builtin_bit_cast(ushort, h);
}

__device__ inline void async16(const void* g, void* l) {
  __builtin_amdgcn_global_load_lds(
      (__attribute__((address_space(1))) unsigned int*)(uintptr_t)g,
      (__attribute__((address_space(3))) unsigned int*)(uintptr_t)l, 16, 0, 0);
}

// ---------------- weight transpose fp32 -> bf16, Wt[n][k] = W[k][n] -------
__global__ __launch_bounds__(256) void wconv_t(
    const float* __restrict__ W, ushort* __restrict__ Wt, int K, int N)
{
  __shared__ float sm[32][33];
  const int n0 = blockIdx.x * 32, k0 = blockIdx.y * 32;
  const int c = threadIdx.x & 31, r0 = threadIdx.x >> 5;
#pragma unroll
  for (int i = 0; i < 4; ++i) {
    const int r = r0 + i * 8;
    sm[r][c] = W[(size_t)(k0 + r) * N + n0 + c];
  }
  __syncthreads();
#pragma unroll
  for (int i = 0; i < 4; ++i) {
    const int r = r0 + i * 8;
    Wt[(size_t)(n0 + r) * K + k0 + c] = f2bf(sm[c][r]);
  }
}

// ---------------- layernorm fp32 -> bf16 ---------------------------------
__global__ __launch_bounds__(256) void ln_kernel(
    const float* __restrict__ x, const float* __restrict__ w,
    const float* __restrict__ b, ushort* __restrict__ out)
{
  const int row = blockIdx.x;
  const int tid = threadIdx.x;
  const float* xr = x + (size_t)row * CDIM;
  float v[3];
  float s1 = 0.f, s2 = 0.f;
#pragma unroll
  for (int i = 0; i < 3; ++i) {
    v[i] = xr[tid + i * 256];
    s1 += v[i];
    s2 += v[i] * v[i];
  }
#pragma unroll
  for (int off = 32; off >= 1; off >>= 1) {
    s1 += __shfl_xor(s1, off, 64);
    s2 += __shfl_xor(s2, off, 64);
  }
  __shared__ float red1[4], red2[4];
  if ((tid & 63) == 0) { red1[tid >> 6] = s1; red2[tid >> 6] = s2; }
  __syncthreads();
  s1 = red1[0] + red1[1] + red1[2] + red1[3];
  s2 = red2[0] + red2[1] + red2[2] + red2[3];
  const float mu = s1 * (1.f / CDIM);
  const float var = s2 * (1.f / CDIM) - mu * mu;
  const float inv = rsqrtf(var + 1e-5f);
#pragma unroll
  for (int i = 0; i < 3; ++i) {
    const int c = tid + i * 256;
    out[(size_t)row * CDIM + c] = f2bf((v[i] - mu) * inv * w[c] + b[c]);
  }
}

// ---------------- 128x128 bf16 MFMA GEMM, C = A @ Bt^T + bias ------------
// A row-major [M][K] bf16, Bt row-major [N][K] bf16.
// EPI 0: bf16 out;  EPI 1: fp32 out = res + v;  EPI 2: bf16 out = gelu(v)
template <int EPI>
__global__ __launch_bounds__(256) void gemm_bt(
    const ushort* __restrict__ A, const ushort* __restrict__ Bt,
    const float* __restrict__ bias, const float* __restrict__ res,
    ushort* __restrict__ outb, float* __restrict__ outf,
    int M, int N, int K)
{
  __shared__ __align__(16) ushort As[128 * 32];
  __shared__ __align__(16) ushort Bs[128 * 32];
  const int tid = threadIdx.x;
  const int lane = tid & 63;
  const int wv = tid >> 6;
  const int rowBase = blockIdx.y * 128;
  const int colBase = blockIdx.x * 128;
  const int wr = (wv >> 1) * 64;
  const int wc = (wv & 1) * 64;

  f32x4 acc[4][4] = {};

  const int e0 = tid * 8;
  const int r0 = e0 >> 5, c0 = e0 & 31;
  const int e1 = (tid + 256) * 8;
  const int r1 = e1 >> 5, c1 = e1 & 31;

  const ushort* Ag0 = A + (size_t)(rowBase + r0) * K + c0;
  const ushort* Ag1 = A + (size_t)(rowBase + r1) * K + c1;
  const ushort* Bg0 = Bt + (size_t)(colBase + r0) * K + c0;
  const ushort* Bg1 = Bt + (size_t)(colBase + r1) * K + c1;

  for (int k0 = 0; k0 < K; k0 += 32) {
    __syncthreads();
    async16(Ag0 + k0, &As[e0]);
    async16(Ag1 + k0, &As[e1]);
    async16(Bg0 + k0, &Bs[e0]);
    async16(Bg1 + k0, &Bs[e1]);
    __syncthreads();
    bf16x8 af[4], bfr[4];
#pragma unroll
    for (int m = 0; m < 4; ++m)
      af[m] = *(const bf16x8*)&As[(wr + m * 16 + (lane & 15)) * 32 + (lane >> 4) * 8];
#pragma unroll
    for (int n = 0; n < 4; ++n)
      bfr[n] = *(const bf16x8*)&Bs[(wc + n * 16 + (lane & 15)) * 32 + (lane >> 4) * 8];
#pragma unroll
    for (int m = 0; m < 4; ++m)
#pragma unroll
      for (int n = 0; n < 4; ++n)
        acc[m][n] = __builtin_amdgcn_mfma_f32_16x16x32_bf16(af[m], bfr[n], acc[m][n], 0, 0, 0);
  }

#pragma unroll
  for (int n = 0; n < 4; ++n) {
    const int gc = colBase + wc + n * 16 + (lane & 15);
    const float bv = bias[gc];
#pragma unroll
    for (int m = 0; m < 4; ++m) {
#pragma unroll
      for (int j = 0; j < 4; ++j) {
        const int gr = rowBase + wr + m * 16 + (lane >> 4) * 4 + j;
        const float v = acc[m][n][j] + bv;
        if (EPI == 0) {
          outb[(size_t)gr * N + gc] = f2bf(v);
        } else if (EPI == 1) {
          outf[(size_t)gr * N + gc] = res[(size_t)gr * N + gc] + v;
        } else {
          const float g = 0.5f * v * (1.0f + erff(v * 0.70710678118654752f));
          outb[(size_t)gr * N + gc] = f2bf(g);
        }
      }
    }
  }
}

// ---------------- causal flash attention, 64x64 tiles, hd=64 -------------
__global__ __launch_bounds__(256) void attn_kernel(
    const ushort* __restrict__ qkv, ushort* __restrict__ att)
{
  __shared__ __align__(16) ushort Qs[64 * 64];
  __shared__ __align__(16) ushort Ks[64 * 64];
  __shared__ __align__(16) ushort Vt[64 * 64];
  __shared__ __align__(16) ushort Ps[4][16 * 64];
  const int tid = threadIdx.x;
  const int lane = tid & 63;
  const int wv = tid >> 6;
  const int qb = blockIdx.x;
  const int h = blockIdx.y;
  const int t0 = qb * 64;
  const int qo = h * HD, ko = CDIM + h * HD, vo = 2 * CDIM + h * HD;

#pragma unroll
  for (int i = 0; i < 2; ++i) {
    const int e = (tid + i * 256) * 8;
    const int r = e >> 6, d = e & 63;
    *(s16x8*)&Qs[r * 64 + d] = *(const s16x8*)&qkv[(size_t)(t0 + r) * (3 * CDIM) + qo + d];
  }

  f32x4 accO[4] = {};
  float mrow[4], lrow[4];
#pragma unroll
  for (int j = 0; j < 4; ++j) { mrow[j] = -INFINITY; lrow[j] = 0.f; }

  for (int kb = 0; kb <= qb; ++kb) {
    __syncthreads();
#pragma unroll
    for (int i = 0; i < 2; ++i) {
      const int e = (tid + i * 256) * 8;
      const int r = e >> 6, d = e & 63;
      *(s16x8*)&Ks[r * 64 + d] = *(const s16x8*)&qkv[(size_t)(kb * 64 + r) * (3 * CDIM) + ko + d];
      const s16x8 vv = *(const s16x8*)&qkv[(size_t)(kb * 64 + r) * (3 * CDIM) + vo + d];
#pragma unroll
      for (int jj = 0; jj < 8; ++jj) Vt[(d + jj) * 64 + r] = (ushort)vv[jj];
    }
    __syncthreads();

    f32x4 accS[4] = {};
#pragma unroll
    for (int kk = 0; kk < 2; ++kk) {
      const bf16x8 a = *(const bf16x8*)&Qs[(wv * 16 + (lane & 15)) * 64 + kk * 32 + (lane >> 4) * 8];
#pragma unroll
      for (int n = 0; n < 4; ++n) {
        const bf16x8 bq = *(const bf16x8*)&Ks[(n * 16 + (lane & 15)) * 64 + kk * 32 + (lane >> 4) * 8];
        accS[n] = __builtin_amdgcn_mfma_f32_16x16x32_bf16(a, bq, accS[n], 0, 0, 0);
      }
    }

    const float scale = 0.125f;
    const bool diag = (kb == qb);
    float mt[4];
#pragma unroll
    for (int j = 0; j < 4; ++j) {
      const int qrow = t0 + wv * 16 + (lane >> 4) * 4 + j;
      float mx = -INFINITY;
#pragma unroll
      for (int n = 0; n < 4; ++n) {
        float s = accS[n][j] * scale;
        if (diag && (kb * 64 + n * 16 + (lane & 15)) > qrow) s = -INFINITY;
        accS[n][j] = s;
        mx = fmaxf(mx, s);
      }
#pragma unroll
      for (int off = 1; off < 16; off <<= 1) mx = fmaxf(mx, __shfl_xor(mx, off, 64));
      mt[j] = mx;
    }

    float alpha[4], psum[4];
#pragma unroll
    for (int j = 0; j < 4; ++j) {
      const float mn = fmaxf(mrow[j], mt[j]);
      alpha[j] = __expf(mrow[j] - mn);
      mrow[j] = mn;
      psum[j] = 0.f;
    }
#pragma unroll
    for (int n = 0; n < 4; ++n)
#pragma unroll
      for (int j = 0; j < 4; ++j) {
        const float pv = __expf(accS[n][j] - mrow[j]);
        accS[n][j] = pv;
        psum[j] += pv;
      }
#pragma unroll
    for (int j = 0; j < 4; ++j) {
#pragma unroll
      for (int off = 1; off < 16; off <<= 1) psum[j] += __shfl_xor(psum[j], off, 64);
      lrow[j] = lrow[j] * alpha[j] + psum[j];
    }
#pragma unroll
    for (int n = 0; n < 4; ++n)
#pragma unroll
      for (int j = 0; j < 4; ++j) accO[n][j] *= alpha[j];

#pragma unroll
    for (int n = 0; n < 4; ++n)
#pragma unroll
      for (int j = 0; j < 4; ++j)
        Ps[wv][((lane >> 4) * 4 + j) * 64 + n * 16 + (lane & 15)] = f2bf(accS[n][j]);

#pragma unroll
    for (int kk = 0; kk < 2; ++kk) {
      const bf16x8 a = *(const bf16x8*)&Ps[wv][(lane & 15) * 64 + kk * 32 + (lane >> 4) * 8];
#pragma unroll
      for (int n = 0; n < 4; ++n) {
        const bf16x8 bv = *(const bf16x8*)&Vt[(n * 16 + (lane & 15)) * 64 + kk * 32 + (lane >> 4) * 8];
        accO[n] = __builtin_amdgcn_mfma_f32_16x16x32_bf16(a, bv, accO[n], 0, 0, 0);
      }
    }
  }

#pragma unroll
  for (int n = 0; n < 4; ++n)
#pragma unroll
    for (int j = 0; j < 4; ++j) {
      const int tq = t0 + wv * 16 + (lane >> 4) * 4 + j;
      const int d = n * 16 + (lane & 15);
      att[(size_t)tq * CDIM + h * HD + d] = f2bf(accO[n][j] / lrow[j]);
    }
}

// -------------------------------------------------------------------------
extern "C" void kernel_launch(void* const* d_in, const int* in_sizes, int n_in,
                              void* d_out, int out_size, void* d_ws, size_t ws_size,
                              hipStream_t stream)
{
  const float* x      = (const float*)d_in[0];
  const float* ln1_w  = (const float*)d_in[1];
  const float* ln1_b  = (const float*)d_in[2];
  const float* W_attn = (const float*)d_in[3];
  const float* b_attn = (const float*)d_in[4];
  const float* W_proj = (const float*)d_in[5];
  const float* b_proj = (const float*)d_in[6];
  const float* ln2_w  = (const float*)d_in[7];
  const float* ln2_b  = (const float*)d_in[8];
  const float* W_fc   = (const float*)d_in[9];
  const float* b_fc   = (const float*)d_in[10];
  const float* W_fc2  = (const float*)d_in[11];
  const float* b_fc2  = (const float*)d_in[12];
  float* out = (float*)d_out;

  char* base = (char*)d_ws;
  size_t off = 0;
  auto alloc = [&](size_t bytes) -> void* {
    void* q = base + off;
    off = (off + bytes + 255) & ~(size_t)255;
    return q;
  };
  ushort* Wt_attn = (ushort*)alloc(768ull * 2304 * 2);
  ushort* Wt_proj = (ushort*)alloc(768ull * 768 * 2);
  ushort* Wt_fc   = (ushort*)alloc(768ull * 3072 * 2);
  ushort* Wt_fc2  = (ushort*)alloc(3072ull * 768 * 2);
  ushort* t_ln    = (ushort*)alloc(4096ull * 768 * 2);
  ushort* t_att   = (ushort*)alloc(4096ull * 768 * 2);
  float*  t_x1    = (float*) alloc(4096ull * 768 * 4);
  ushort* t_big   = (ushort*)alloc(4096ull * 3072 * 2); // qkv, then mlp hidden
  ushort* t_qkv = t_big;
  ushort* t_h   = t_big;

  // weight conversions (transposed bf16)
  wconv_t<<<dim3(2304 / 32, 768 / 32), 256, 0, stream>>>(W_attn, Wt_attn, 768, 2304);
  wconv_t<<<dim3(768 / 32, 768 / 32), 256, 0, stream>>>(W_proj, Wt_proj, 768, 768);
  wconv_t<<<dim3(3072 / 32, 768 / 32), 256, 0, stream>>>(W_fc, Wt_fc, 768, 3072);
  wconv_t<<<dim3(768 / 32, 3072 / 32), 256, 0, stream>>>(W_fc2, Wt_fc2, 3072, 768);

  // LN1
  ln_kernel<<<4096, 256, 0, stream>>>(x, ln1_w, ln1_b, t_ln);
  // QKV
  gemm_bt<0><<<dim3(2304 / 128, 4096 / 128), 256, 0, stream>>>(
      t_ln, Wt_attn, b_attn, nullptr, t_qkv, nullptr, 4096, 2304, 768);
  // attention
  attn_kernel<<<dim3(64, 12), 256, 0, stream>>>(t_qkv, t_att);
  // proj + residual -> x1 (fp32)
  gemm_bt<1><<<dim3(768 / 128, 4096 / 128), 256, 0, stream>>>(
      t_att, Wt_proj, b_proj, x, nullptr, t_x1, 4096, 768, 768);
  // LN2
  ln_kernel<<<4096, 256, 0, stream>>>(t_x1, ln2_w, ln2_b, t_ln);
  // FC + gelu
  gemm_bt<2><<<dim3(3072 / 128, 4096 / 128), 256, 0, stream>>>(
      t_ln, Wt_fc, b_fc, nullptr, t_h, nullptr, 4096, 3072, 768);
  // FC2 + residual -> out (fp32)
  gemm_bt<1><<<dim3(768 / 128, 4096 / 128), 256, 0, stream>>>(
      t_h, Wt_fc2, b_fc2, t_x1, nullptr, out, 4096, 768, 3072);
}

// Round 2
// 365.608 us; speedup vs baseline: 1.3366x; 1.3366x over previous
//
#include <hip/hip_runtime.h>
#include <hip/hip_bf16.h>
#include <math.h>

#define TSEQ 4096
#define CDIM 768
#define NH 12
#define HD 64

typedef float f32x4 __attribute__((ext_vector_type(4)));
typedef __bf16 bf16x8 __attribute__((ext_vector_type(8)));
typedef short s16x8 __attribute__((ext_vector_type(8)));

__device__ inline ushort f2bf(float f) {
  __hip_bfloat16 h = __float2bfloat16(f);
  return __builtin_bit_cast(ushort, h);
}

__device__ inline void async16(const void* g, void* l) {
  __builtin_amdgcn_global_load_lds(
      (__attribute__((address_space(1))) unsigned int*)(uintptr_t)g,
      (__attribute__((address_space(3))) unsigned int*)(uintptr_t)l, 16, 0, 0);
}

__device__ inline void barrier_vm0() {
  asm volatile("s_waitcnt vmcnt(0)" ::: "memory");
  __builtin_amdgcn_sched_barrier(0);
  __builtin_amdgcn_s_barrier();
  __builtin_amdgcn_sched_barrier(0);
}
__device__ inline void barrier_lgkm0() {
  asm volatile("s_waitcnt lgkmcnt(0)" ::: "memory");
  __builtin_amdgcn_sched_barrier(0);
  __builtin_amdgcn_s_barrier();
  __builtin_amdgcn_sched_barrier(0);
}

// swizzled fragment read from a [64][64] bf16 tile with row-chunk XOR swizzle
__device__ inline bf16x8 frag_read(const ushort* base, int row, int kk, int lane) {
  const int byte = row * 128 + ((((kk * 4 + (lane >> 4)) ^ (row & 7))) << 4);
  return *(const bf16x8*)((const char*)base + byte);
}

// ---------------- weight transpose fp32 -> bf16, Wt[n][k] = W[k][n] -------
__global__ __launch_bounds__(256) void wconv_t(
    const float* __restrict__ W, ushort* __restrict__ Wt, int K, int N)
{
  __shared__ float sm[32][33];
  const int n0 = blockIdx.x * 32, k0 = blockIdx.y * 32;
  const int c = threadIdx.x & 31, r0 = threadIdx.x >> 5;
#pragma unroll
  for (int i = 0; i < 4; ++i) {
    const int r = r0 + i * 8;
    sm[r][c] = W[(size_t)(k0 + r) * N + n0 + c];
  }
  __syncthreads();
#pragma unroll
  for (int i = 0; i < 4; ++i) {
    const int r = r0 + i * 8;
    Wt[(size_t)(n0 + r) * K + k0 + c] = f2bf(sm[c][r]);
  }
}

// ---------------- layernorm fp32 -> bf16 ---------------------------------
__global__ __launch_bounds__(256) void ln_kernel(
    const float* __restrict__ x, const float* __restrict__ w,
    const float* __restrict__ b, ushort* __restrict__ out)
{
  const int row = blockIdx.x;
  const int tid = threadIdx.x;
  const float* xr = x + (size_t)row * CDIM;
  float v[3];
  float s1 = 0.f, s2 = 0.f;
#pragma unroll
  for (int i = 0; i < 3; ++i) {
    v[i] = xr[tid + i * 256];
    s1 += v[i];
    s2 += v[i] * v[i];
  }
#pragma unroll
  for (int off = 32; off >= 1; off >>= 1) {
    s1 += __shfl_xor(s1, off, 64);
    s2 += __shfl_xor(s2, off, 64);
  }
  __shared__ float red1[4], red2[4];
  if ((tid & 63) == 0) { red1[tid >> 6] = s1; red2[tid >> 6] = s2; }
  __syncthreads();
  s1 = red1[0] + red1[1] + red1[2] + red1[3];
  s2 = red2[0] + red2[1] + red2[2] + red2[3];
  const float mu = s1 * (1.f / CDIM);
  const float var = s2 * (1.f / CDIM) - mu * mu;
  const float inv = rsqrtf(var + 1e-5f);
#pragma unroll
  for (int i = 0; i < 3; ++i) {
    const int c = tid + i * 256;
    out[(size_t)row * CDIM + c] = f2bf((v[i] - mu) * inv * w[c] + b[c]);
  }
}

// ---------------- 128x128 bf16 MFMA GEMM, C = A @ Bt^T + bias ------------
template <int EPI>
__global__ __launch_bounds__(256) void gemm_bt(
    const ushort* __restrict__ A, const ushort* __restrict__ Bt,
    const float* __restrict__ bias, const float* __restrict__ res,
    ushort* __restrict__ outb, float* __restrict__ outf,
    int M, int N, int K)
{
  __shared__ __align__(16) ushort As[128 * 32];
  __shared__ __align__(16) ushort Bs[128 * 32];
  const int tid = threadIdx.x;
  const int lane = tid & 63;
  const int wv = tid >> 6;
  const int rowBase = blockIdx.y * 128;
  const int colBase = blockIdx.x * 128;
  const int wr = (wv >> 1) * 64;
  const int wc = (wv & 1) * 64;

  f32x4 acc[4][4] = {};

  const int e0 = tid * 8;
  const int r0 = e0 >> 5, c0 = e0 & 31;
  const int e1 = (tid + 256) * 8;
  const int r1 = e1 >> 5, c1 = e1 & 31;

  const ushort* Ag0 = A + (size_t)(rowBase + r0) * K + c0;
  const ushort* Ag1 = A + (size_t)(rowBase + r1) * K + c1;
  const ushort* Bg0 = Bt + (size_t)(colBase + r0) * K + c0;
  const ushort* Bg1 = Bt + (size_t)(colBase + r1) * K + c1;

  for (int k0 = 0; k0 < K; k0 += 32) {
    __syncthreads();
    async16(Ag0 + k0, &As[e0]);
    async16(Ag1 + k0, &As[e1]);
    async16(Bg0 + k0, &Bs[e0]);
    async16(Bg1 + k0, &Bs[e1]);
    __syncthreads();
    bf16x8 af[4], bfr[4];
#pragma unroll
    for (int m = 0; m < 4; ++m)
      af[m] = *(const bf16x8*)&As[(wr + m * 16 + (lane & 15)) * 32 + (lane >> 4) * 8];
#pragma unroll
    for (int n = 0; n < 4; ++n)
      bfr[n] = *(const bf16x8*)&Bs[(wc + n * 16 + (lane & 15)) * 32 + (lane >> 4) * 8];
#pragma unroll
    for (int m = 0; m < 4; ++m)
#pragma unroll
      for (int n = 0; n < 4; ++n)
        acc[m][n] = __builtin_amdgcn_mfma_f32_16x16x32_bf16(af[m], bfr[n], acc[m][n], 0, 0, 0);
  }

#pragma unroll
  for (int n = 0; n < 4; ++n) {
    const int gc = colBase + wc + n * 16 + (lane & 15);
    const float bv = bias[gc];
#pragma unroll
    for (int m = 0; m < 4; ++m) {
#pragma unroll
      for (int j = 0; j < 4; ++j) {
        const int gr = rowBase + wr + m * 16 + (lane >> 4) * 4 + j;
        const float v = acc[m][n][j] + bv;
        if (EPI == 0) {
          outb[(size_t)gr * N + gc] = f2bf(v);
        } else if (EPI == 1) {
          outf[(size_t)gr * N + gc] = res[(size_t)gr * N + gc] + v;
        } else {
          const float g = 0.5f * v * (1.0f + erff(v * 0.70710678118654752f));
          outb[(size_t)gr * N + gc] = f2bf(g);
        }
      }
    }
  }
}

// ---------------- causal flash attention, 64x64 tiles, hd=64 -------------
// Swizzled LDS, gload_lds K-staging (pre-swizzled src), reg-staged V^T,
// cross-iter K/V prefetch, raw barriers with counted waits.
__global__ __launch_bounds__(256) void attn_kernel(
    const ushort* __restrict__ qkv, ushort* __restrict__ att)
{
  __shared__ __align__(16) ushort QP[64 * 64];      // Q tile, then reused as P
  __shared__ __align__(16) ushort Ks[2][64 * 64];
  __shared__ __align__(16) ushort Vt[2][64 * 64];   // V transposed [d][t]

  const int tid = threadIdx.x;
  const int lane = tid & 63;
  const int wv = tid >> 6;
  const int qb = (int)gridDim.x - 1 - (int)blockIdx.x;  // heavy blocks first
  const int h = blockIdx.y;
  const int t0 = qb * 64;
  const size_t rs = 3 * CDIM;
  const int qo = h * HD, ko = CDIM + h * HD, vo = 2 * CDIM + h * HD;

  // K/Q staging geometry: LDS slot L (bytes); row r = L>>7, chunk cc = (L>>4)&7,
  // source chunk = cc ^ (r&7)  (pre-swizzled source -> swizzled layout, linear dest)
  const int L0 = tid * 16, L1 = (tid + 256) * 16;
  const int r_0 = L0 >> 7, c_0 = ((L0 >> 4) & 7) ^ (r_0 & 7);
  const int r_1 = L1 >> 7, c_1 = ((L1 >> 4) & 7) ^ (r_1 & 7);
  const ushort* kg0 = qkv + (size_t)r_0 * rs + ko + c_0 * 8;
  const ushort* kg1 = qkv + (size_t)r_1 * rs + ko + c_1 * 8;

  // V reg-staging geometry: thread covers rows {vt, vt+1}, cols [vd, vd+8)
  const int vt = (tid >> 3) * 2;
  const int vd = (tid & 7) * 8;
  const ushort* vg = qkv + (size_t)vt * rs + vo + vd;

  // prologue: stage Q, K0; load V0
  async16(qkv + (size_t)(t0 + r_0) * rs + qo + c_0 * 8, (char*)QP + L0);
  async16(qkv + (size_t)(t0 + r_1) * rs + qo + c_1 * 8, (char*)QP + L1);
  async16(kg0, (char*)Ks[0] + L0);
  async16(kg1, (char*)Ks[0] + L1);
  s16x8 vA0 = *(const s16x8*)(vg);
  s16x8 vA1 = *(const s16x8*)(vg + rs);
  s16x8 vB0, vB1;

  bf16x8 aq0, aq1;
  f32x4 accO[4] = {};
  float mrow[4], lrow[4];
#pragma unroll
  for (int j = 0; j < 4; ++j) { mrow[j] = -INFINITY; lrow[j] = 0.f; }

  const float scale = 0.125f;
  const int swzv = ((lane & 15) >> 1) & 7;   // Vt read swizzle selector

  auto body = [&](int kb, int cur, s16x8& vL0, s16x8& vL1, s16x8& vN0, s16x8& vN1) {
    barrier_vm0();   // K(kb) staged, V(kb) in vL; safe to touch buffers

    if (kb == 0) {
      aq0 = frag_read(QP, wv * 16 + (lane & 15), 0, lane);
      aq1 = frag_read(QP, wv * 16 + (lane & 15), 1, lane);
    }
    // prefetch next tile
    if (kb + 1 <= qb) {
      const size_t koff = (size_t)(kb + 1) * 64 * rs;
      async16(kg0 + koff, (char*)Ks[cur ^ 1] + L0);
      async16(kg1 + koff, (char*)Ks[cur ^ 1] + L1);
      vN0 = *(const s16x8*)(vg + koff);
      vN1 = *(const s16x8*)(vg + koff + rs);
    }

    // QK^T
    f32x4 accS[4] = {};
#pragma unroll
    for (int kk = 0; kk < 2; ++kk) {
      const bf16x8 a = kk ? aq1 : aq0;
#pragma unroll
      for (int n = 0; n < 4; ++n) {
        const bf16x8 bq = frag_read(Ks[cur], n * 16 + (lane & 15), kk, lane);
        accS[n] = __builtin_amdgcn_mfma_f32_16x16x32_bf16(a, bq, accS[n], 0, 0, 0);
      }
    }

    // stage V^T (pack 2 t-values per b32, swizzled)
#pragma unroll
    for (int jj = 0; jj < 8; ++jj) {
      const int d = vd + jj;
      const uint val = (uint)(ushort)vL0[jj] | ((uint)(ushort)vL1[jj] << 16);
      const int byte = d * 128 + ((vt * 2) ^ (((d >> 1) & 7) << 4));
      *(uint*)((char*)Vt[cur] + byte) = val;
    }

    // mask + online softmax
    const bool diag = (kb == qb);
    float mt[4];
#pragma unroll
    for (int j = 0; j < 4; ++j) {
      const int qrow = t0 + wv * 16 + (lane >> 4) * 4 + j;
      float mx = -INFINITY;
#pragma unroll
      for (int n = 0; n < 4; ++n) {
        float s = accS[n][j] * scale;
        if (diag && (kb * 64 + n * 16 + (lane & 15)) > qrow) s = -INFINITY;
        accS[n][j] = s;
        mx = fmaxf(mx, s);
      }
#pragma unroll
      for (int off = 1; off < 16; off <<= 1) mx = fmaxf(mx, __shfl_xor(mx, off, 64));
      mt[j] = mx;
    }
    float alpha[4], psum[4];
#pragma unroll
    for (int j = 0; j < 4; ++j) {
      const float mn = fmaxf(mrow[j], mt[j]);
      alpha[j] = __expf(mrow[j] - mn);
      mrow[j] = mn;
      psum[j] = 0.f;
    }
#pragma unroll
    for (int n = 0; n < 4; ++n)
#pragma unroll
      for (int j = 0; j < 4; ++j) {
        const float pv = __expf(accS[n][j] - mrow[j]);
        accS[n][j] = pv;
        psum[j] += pv;
      }
#pragma unroll
    for (int j = 0; j < 4; ++j) {
#pragma unroll
      for (int off = 1; off < 16; off <<= 1) psum[j] += __shfl_xor(psum[j], off, 64);
      lrow[j] = lrow[j] * alpha[j] + psum[j];
    }
#pragma unroll
    for (int n = 0; n < 4; ++n)
#pragma unroll
      for (int j = 0; j < 4; ++j) accO[n][j] *= alpha[j];

    // write P (swizzled scalar b16)
#pragma unroll
    for (int n = 0; n < 4; ++n)
#pragma unroll
      for (int j = 0; j < 4; ++j) {
        const int row = wv * 16 + (lane >> 4) * 4 + j;
        const int col = n * 16 + (lane & 15);
        const int byte = row * 128 + ((col * 2) ^ ((row & 7) << 4));
        *(ushort*)((char*)QP + byte) = f2bf(accS[n][j]);
      }

    barrier_lgkm0();   // P + V^T visible to all waves

    // PV
#pragma unroll
    for (int kk = 0; kk < 2; ++kk) {
      const bf16x8 a = frag_read(QP, wv * 16 + (lane & 15), kk, lane);
#pragma unroll
      for (int n = 0; n < 4; ++n) {
        const int byte = (n * 16 + (lane & 15)) * 128 +
                         ((kk * 64 + (lane >> 4) * 16) ^ (swzv << 4));
        const bf16x8 bv = *(const bf16x8*)((const char*)Vt[cur] + byte);
        accO[n] = __builtin_amdgcn_mfma_f32_16x16x32_bf16(a, bv, accO[n], 0, 0, 0);
      }
    }
  };

  for (int kb = 0; kb <= qb; kb += 2) {
    body(kb, 0, vA0, vA1, vB0, vB1);
    if (kb + 1 <= qb) body(kb + 1, 1, vB0, vB1, vA0, vA1);
  }

#pragma unroll
  for (int n = 0; n < 4; ++n)
#pragma unroll
    for (int j = 0; j < 4; ++j) {
      const int tq = t0 + wv * 16 + (lane >> 4) * 4 + j;
      const int d = n * 16 + (lane & 15);
      att[(size_t)tq * CDIM + h * HD + d] = f2bf(accO[n][j] / lrow[j]);
    }
}

// -------------------------------------------------------------------------
extern "C" void kernel_launch(void* const* d_in, const int* in_sizes, int n_in,
                              void* d_out, int out_size, void* d_ws, size_t ws_size,
                              hipStream_t stream)
{
  const float* x      = (const float*)d_in[0];
  const float* ln1_w  = (const float*)d_in[1];
  const float* ln1_b  = (const float*)d_in[2];
  const float* W_attn = (const float*)d_in[3];
  const float* b_attn = (const float*)d_in[4];
  const float* W_proj = (const float*)d_in[5];
  const float* b_proj = (const float*)d_in[6];
  const float* ln2_w  = (const float*)d_in[7];
  const float* ln2_b  = (const float*)d_in[8];
  const float* W_fc   = (const float*)d_in[9];
  const float* b_fc   = (const float*)d_in[10];
  const float* W_fc2  = (const float*)d_in[11];
  const float* b_fc2  = (const float*)d_in[12];
  float* out = (float*)d_out;

  char* base = (char*)d_ws;
  size_t off = 0;
  auto alloc = [&](size_t bytes) -> void* {
    void* q = base + off;
    off = (off + bytes + 255) & ~(size_t)255;
    return q;
  };
  ushort* Wt_attn = (ushort*)alloc(768ull * 2304 * 2);
  ushort* Wt_proj = (ushort*)alloc(768ull * 768 * 2);
  ushort* Wt_fc   = (ushort*)alloc(768ull * 3072 * 2);
  ushort* Wt_fc2  = (ushort*)alloc(3072ull * 768 * 2);
  ushort* t_ln    = (ushort*)alloc(4096ull * 768 * 2);
  ushort* t_att   = (ushort*)alloc(4096ull * 768 * 2);
  float*  t_x1    = (float*) alloc(4096ull * 768 * 4);
  ushort* t_big   = (ushort*)alloc(4096ull * 3072 * 2);
  ushort* t_qkv = t_big;
  ushort* t_h   = t_big;

  wconv_t<<<dim3(2304 / 32, 768 / 32), 256, 0, stream>>>(W_attn, Wt_attn, 768, 2304);
  wconv_t<<<dim3(768 / 32, 768 / 32), 256, 0, stream>>>(W_proj, Wt_proj, 768, 768);
  wconv_t<<<dim3(3072 / 32, 768 / 32), 256, 0, stream>>>(W_fc, Wt_fc, 768, 3072);
  wconv_t<<<dim3(768 / 32, 3072 / 32), 256, 0, stream>>>(W_fc2, Wt_fc2, 3072, 768);

  ln_kernel<<<4096, 256, 0, stream>>>(x, ln1_w, ln1_b, t_ln);
  gemm_bt<0><<<dim3(2304 / 128, 4096 / 128), 256, 0, stream>>>(
      t_ln, Wt_attn, b_attn, nullptr, t_qkv, nullptr, 4096, 2304, 768);
  attn_kernel<<<dim3(64, 12), 256, 0, stream>>>(t_qkv, t_att);
  gemm_bt<1><<<dim3(768 / 128, 4096 / 128), 256, 0, stream>>>(
      t_att, Wt_proj, b_proj, x, nullptr, t_x1, 4096, 768, 768);
  ln_kernel<<<4096, 256, 0, stream>>>(t_x1, ln2_w, ln2_b, t_ln);
  gemm_bt<2><<<dim3(3072 / 128, 4096 / 128), 256, 0, stream>>>(
      t_ln, Wt_fc, b_fc, nullptr, t_h, nullptr, 4096, 3072, 768);
  gemm_bt<1><<<dim3(768 / 128, 4096 / 128), 256, 0, stream>>>(
      t_h, Wt_fc2, b_fc2, t_x1, nullptr, out, 4096, 768, 3072);
}

// Round 3
// 243.394 us; speedup vs baseline: 2.0078x; 1.5021x over previous
//
#include <hip/hip_runtime.h>
#include <hip/hip_bf16.h>
#include <math.h>

#define TSEQ 4096
#define CDIM 768
#define NH 12
#define HD 64

typedef float f32x4 __attribute__((ext_vector_type(4)));
typedef __bf16 bf16x8 __attribute__((ext_vector_type(8)));
typedef short s16x8 __attribute__((ext_vector_type(8)));

__device__ inline ushort f2bf(float f) {
  __hip_bfloat16 h = __float2bfloat16(f);
  return __builtin_bit_cast(ushort, h);
}

__device__ inline void async16(const void* g, void* l) {
  __builtin_amdgcn_global_load_lds(
      (__attribute__((address_space(1))) unsigned int*)(uintptr_t)g,
      (__attribute__((address_space(3))) unsigned int*)(uintptr_t)l, 16, 0, 0);
}

__device__ inline void barrier_all() {
  asm volatile("s_waitcnt vmcnt(0) lgkmcnt(0)" ::: "memory");
  __builtin_amdgcn_sched_barrier(0);
  __builtin_amdgcn_s_barrier();
  __builtin_amdgcn_sched_barrier(0);
}

// v_exp_f32 computes 2^x; s_nop covers the TRANS->VALU hazard
__device__ inline float exp2_fast(float x) {
  float r;
  asm volatile("v_exp_f32 %0, %1\n\ts_nop 0" : "=v"(r) : "v"(x));
  return r;
}

// swizzled fragment read from a [64][64] bf16 tile with row-chunk XOR swizzle
__device__ inline bf16x8 frag_read(const ushort* base, int row, int kk, int lane) {
  const int byte = row * 128 + ((((kk * 4 + (lane >> 4)) ^ (row & 7))) << 4);
  return *(const bf16x8*)((const char*)base + byte);
}

// ---------------- weight transpose fp32 -> bf16, Wt[n][k] = W[k][n] -------
__global__ __launch_bounds__(256) void wconv_t(
    const float* __restrict__ W, ushort* __restrict__ Wt, int K, int N)
{
  __shared__ float sm[32][33];
  const int n0 = blockIdx.x * 32, k0 = blockIdx.y * 32;
  const int c = threadIdx.x & 31, r0 = threadIdx.x >> 5;
#pragma unroll
  for (int i = 0; i < 4; ++i) {
    const int r = r0 + i * 8;
    sm[r][c] = W[(size_t)(k0 + r) * N + n0 + c];
  }
  __syncthreads();
#pragma unroll
  for (int i = 0; i < 4; ++i) {
    const int r = r0 + i * 8;
    Wt[(size_t)(n0 + r) * K + k0 + c] = f2bf(sm[c][r]);
  }
}

// ---------------- layernorm fp32 -> bf16 ---------------------------------
__global__ __launch_bounds__(256) void ln_kernel(
    const float* __restrict__ x, const float* __restrict__ w,
    const float* __restrict__ b, ushort* __restrict__ out)
{
  const int row = blockIdx.x;
  const int tid = threadIdx.x;
  const float* xr = x + (size_t)row * CDIM;
  float v[3];
  float s1 = 0.f, s2 = 0.f;
#pragma unroll
  for (int i = 0; i < 3; ++i) {
    v[i] = xr[tid + i * 256];
    s1 += v[i];
    s2 += v[i] * v[i];
  }
#pragma unroll
  for (int off = 32; off >= 1; off >>= 1) {
    s1 += __shfl_xor(s1, off, 64);
    s2 += __shfl_xor(s2, off, 64);
  }
  __shared__ float red1[4], red2[4];
  if ((tid & 63) == 0) { red1[tid >> 6] = s1; red2[tid >> 6] = s2; }
  __syncthreads();
  s1 = red1[0] + red1[1] + red1[2] + red1[3];
  s2 = red2[0] + red2[1] + red2[2] + red2[3];
  const float mu = s1 * (1.f / CDIM);
  const float var = s2 * (1.f / CDIM) - mu * mu;
  const float inv = rsqrtf(var + 1e-5f);
#pragma unroll
  for (int i = 0; i < 3; ++i) {
    const int c = tid + i * 256;
    out[(size_t)row * CDIM + c] = f2bf((v[i] - mu) * inv * w[c] + b[c]);
  }
}

// ---------------- 128xBN bf16 MFMA GEMM, C = A @ Bt^T + bias -------------
// EPI 0: bf16 out;  EPI 1: fp32 out = res + v;  EPI 2: bf16 out = gelu(v)
template <int EPI, int BN>
__global__ __launch_bounds__(256) void gemm_bt(
    const ushort* __restrict__ A, const ushort* __restrict__ Bt,
    const float* __restrict__ bias, const float* __restrict__ res,
    ushort* __restrict__ outb, float* __restrict__ outf,
    int M, int N, int K)
{
  constexpr int NW = BN / 32;   // n-fragments per wave
  __shared__ __align__(16) ushort As[128 * 32];
  __shared__ __align__(16) ushort Bs[BN * 32];
  const int tid = threadIdx.x;
  const int lane = tid & 63;
  const int wv = tid >> 6;
  const int rowBase = blockIdx.y * 128;
  const int colBase = blockIdx.x * BN;
  const int wr = (wv >> 1) * 64;
  const int wc = (wv & 1) * (BN / 2);

  f32x4 acc[4][NW] = {};

  const int e0 = tid * 8;
  const int r0 = e0 >> 5, c0 = e0 & 31;
  const int e1 = (tid + 256) * 8;
  const int r1 = e1 >> 5, c1 = e1 & 31;

  const ushort* Ag0 = A + (size_t)(rowBase + r0) * K + c0;
  const ushort* Ag1 = A + (size_t)(rowBase + r1) * K + c1;
  const ushort* Bg0 = Bt + (size_t)(colBase + r0) * K + c0;
  const ushort* Bg1 = Bt + (size_t)(colBase + r1) * K + c1;

  for (int k0 = 0; k0 < K; k0 += 32) {
    __syncthreads();
    async16(Ag0 + k0, &As[e0]);
    async16(Ag1 + k0, &As[e1]);
    async16(Bg0 + k0, &Bs[e0]);
    if (BN == 128) async16(Bg1 + k0, &Bs[e1]);
    __syncthreads();
    bf16x8 af[4], bfr[NW];
#pragma unroll
    for (int m = 0; m < 4; ++m)
      af[m] = *(const bf16x8*)&As[(wr + m * 16 + (lane & 15)) * 32 + (lane >> 4) * 8];
#pragma unroll
    for (int n = 0; n < NW; ++n)
      bfr[n] = *(const bf16x8*)&Bs[(wc + n * 16 + (lane & 15)) * 32 + (lane >> 4) * 8];
#pragma unroll
    for (int m = 0; m < 4; ++m)
#pragma unroll
      for (int n = 0; n < NW; ++n)
        acc[m][n] = __builtin_amdgcn_mfma_f32_16x16x32_bf16(af[m], bfr[n], acc[m][n], 0, 0, 0);
  }

#pragma unroll
  for (int n = 0; n < NW; ++n) {
    const int gc = colBase + wc + n * 16 + (lane & 15);
    const float bv = bias[gc];
#pragma unroll
    for (int m = 0; m < 4; ++m) {
#pragma unroll
      for (int j = 0; j < 4; ++j) {
        const int gr = rowBase + wr + m * 16 + (lane >> 4) * 4 + j;
        const float v = acc[m][n][j] + bv;
        if (EPI == 0) {
          outb[(size_t)gr * N + gc] = f2bf(v);
        } else if (EPI == 1) {
          outf[(size_t)gr * N + gc] = res[(size_t)gr * N + gc] + v;
        } else {
          const float g = 0.5f * v * (1.0f + erff(v * 0.70710678118654752f));
          outb[(size_t)gr * N + gc] = f2bf(g);
        }
      }
    }
  }
}

// ---------------- causal flash attention, 64x64 tiles, hd=64 -------------
// Fixed-max softmax (no per-row max/sum reduces), l via MFMA ones-column,
// one barrier per K-tile, snake-balanced (qb,h) assignment.
__global__ __launch_bounds__(256) void attn_kernel(
    const ushort* __restrict__ qkv, ushort* __restrict__ att)
{
  __shared__ __align__(16) ushort QP[64 * 64];      // Q tile, then reused as P
  __shared__ __align__(16) ushort Ks[2][64 * 64];
  __shared__ __align__(16) ushort Vt[2][80 * 64];   // V^T [d][t]; rows 64..79: ones/zeros

  const int tid = threadIdx.x;
  const int lane = tid & 63;
  const int wv = tid >> 6;
  // snake remap: CU's resident blocks {p, 511-p, 512+p} -> balanced work
  const int p = blockIdx.x & 255, g = blockIdx.x >> 8;
  const int item = (g & 1) ? (g * 256 + 255 - p) : (g * 256 + p);
  const int qb = 63 - (item / 12);
  const int h = item % 12;
  const int t0 = qb * 64;
  const size_t rs = 3 * CDIM;
  const int qo = h * HD, ko = CDIM + h * HD, vo = 2 * CDIM + h * HD;

  const float cexp = 0.18033688f;            // 0.125 * log2(e)
  const float cbias = -32.0f * 0.18033688f;  // fixed max M_raw = 32

  // K/Q staging: pre-swizzled global source -> linear LDS dest
  const int L0 = tid * 16, L1 = (tid + 256) * 16;
  const int r_0 = L0 >> 7, c_0 = ((L0 >> 4) & 7) ^ (r_0 & 7);
  const int r_1 = L1 >> 7, c_1 = ((L1 >> 4) & 7) ^ (r_1 & 7);
  const ushort* kg0 = qkv + (size_t)r_0 * rs + ko + c_0 * 8;
  const ushort* kg1 = qkv + (size_t)r_1 * rs + ko + c_1 * 8;

  // V reg-staging: thread covers rows {vt, vt+1}, cols [vd, vd+8)
  const int vt = (tid >> 3) * 2;
  const int vd = (tid & 7) * 8;
  const ushort* vg = qkv + (size_t)vt * rs + vo + vd;

  // ones/zeros rows (64..79) of both Vt buffers
  for (int i = tid; i < 1024; i += 256) {
    const int buf = i >> 9;
    const int rem = i & 511;
    const int d = 64 + (rem >> 5);
    const int tp = rem & 31;
    const int byte = d * 128 + ((tp * 4) ^ (((d >> 1) & 7) << 4));
    *(uint*)((char*)Vt[buf] + byte) = (d == 64) ? 0x3f803f80u : 0u;
  }

  // prologue: stage Q, K0; stage V^T(0)
  async16(qkv + (size_t)(t0 + r_0) * rs + qo + c_0 * 8, (char*)QP + L0);
  async16(qkv + (size_t)(t0 + r_1) * rs + qo + c_1 * 8, (char*)QP + L1);
  async16(kg0, (char*)Ks[0] + L0);
  async16(kg1, (char*)Ks[0] + L1);
  {
    const s16x8 v0 = *(const s16x8*)(vg);
    const s16x8 v1 = *(const s16x8*)(vg + rs);
#pragma unroll
    for (int jj = 0; jj < 8; ++jj) {
      const int d = vd + jj;
      const uint val = (uint)(ushort)v0[jj] | ((uint)(ushort)v1[jj] << 16);
      const int byte = d * 128 + ((vt * 2) ^ (((d >> 1) & 7) << 4));
      *(uint*)((char*)Vt[0] + byte) = val;
    }
  }

  bf16x8 aq0, aq1;
  f32x4 accO[5] = {};
  const int swzv = ((lane & 15) >> 1) & 7;

  auto body = [&](int kb, int cur, bool diag) {
    barrier_all();   // K(kb), V^T(kb) staged & visible

    if (kb == 0) {
      aq0 = frag_read(QP, wv * 16 + (lane & 15), 0, lane);
      aq1 = frag_read(QP, wv * 16 + (lane & 15), 1, lane);
    }
    // prefetch next tile
    s16x8 vN0, vN1;
    const bool pre = (kb + 1 <= qb);
    if (pre) {
      const size_t koff = (size_t)(kb + 1) * 64 * rs;
      async16(kg0 + koff, (char*)Ks[cur ^ 1] + L0);
      async16(kg1 + koff, (char*)Ks[cur ^ 1] + L1);
      vN0 = *(const s16x8*)(vg + koff);
      vN1 = *(const s16x8*)(vg + koff + rs);
    }

    // QK^T
    f32x4 accS[4] = {};
#pragma unroll
    for (int kk = 0; kk < 2; ++kk) {
      const bf16x8 a = kk ? aq1 : aq0;
#pragma unroll
      for (int n = 0; n < 4; ++n) {
        const bf16x8 bq = frag_read(Ks[cur], n * 16 + (lane & 15), kk, lane);
        accS[n] = __builtin_amdgcn_mfma_f32_16x16x32_bf16(a, bq, accS[n], 0, 0, 0);
      }
    }

    // p = 2^(s*c - M*c), masked on diagonal tile; write P (swizzled)
#pragma unroll
    for (int n = 0; n < 4; ++n)
#pragma unroll
      for (int j = 0; j < 4; ++j) {
        float pv = exp2_fast(fmaf(accS[n][j], cexp, cbias));
        if (diag) {
          const int col = n * 16 + (lane & 15);
          const int row = wv * 16 + (lane >> 4) * 4 + j;
          if (col > row) pv = 0.f;
        }
        const int row = wv * 16 + (lane >> 4) * 4 + j;
        const int col = n * 16 + (lane & 15);
        const int byte = row * 128 + ((col * 2) ^ ((row & 7) << 4));
        *(ushort*)((char*)QP + byte) = f2bf(pv);
      }

    // PV (+ ones-column -> l): wave-local P, compiler orders LDS ops
#pragma unroll
    for (int kk = 0; kk < 2; ++kk) {
      const bf16x8 a = frag_read(QP, wv * 16 + (lane & 15), kk, lane);
#pragma unroll
      for (int n = 0; n < 5; ++n) {
        const int byte = (n * 16 + (lane & 15)) * 128 +
                         ((kk * 64 + (lane >> 4) * 16) ^ (swzv << 4));
        const bf16x8 bv = *(const bf16x8*)((const char*)Vt[cur] + byte);
        accO[n] = __builtin_amdgcn_mfma_f32_16x16x32_bf16(a, bv, accO[n], 0, 0, 0);
      }
    }

    // stage V^T(kb+1) into the other buffer (visible after next barrier)
    if (pre) {
#pragma unroll
      for (int jj = 0; jj < 8; ++jj) {
        const int d = vd + jj;
        const uint val = (uint)(ushort)vN0[jj] | ((uint)(ushort)vN1[jj] << 16);
        const int byte = d * 128 + ((vt * 2) ^ (((d >> 1) & 7) << 4));
        *(uint*)((char*)Vt[cur ^ 1] + byte) = val;
      }
    }
  };

  int cur = 0;
  for (int kb = 0; kb < qb; ++kb) {
    body(kb, cur, false);
    cur ^= 1;
  }
  body(qb, cur, true);

  // l[j] lives in the ones-column (lane&15 == 0 of each 16-lane group)
  float inv[4];
#pragma unroll
  for (int j = 0; j < 4; ++j) {
    const float l = __shfl(accO[4][j], lane & 48, 64);
    inv[j] = 1.0f / l;
  }
#pragma unroll
  for (int n = 0; n < 4; ++n)
#pragma unroll
    for (int j = 0; j < 4; ++j) {
      const int tq = t0 + wv * 16 + (lane >> 4) * 4 + j;
      const int d = n * 16 + (lane & 15);
      att[(size_t)tq * CDIM + h * HD + d] = f2bf(accO[n][j] * inv[j]);
    }
}

// -------------------------------------------------------------------------
extern "C" void kernel_launch(void* const* d_in, const int* in_sizes, int n_in,
                              void* d_out, int out_size, void* d_ws, size_t ws_size,
                              hipStream_t stream)
{
  const float* x      = (const float*)d_in[0];
  const float* ln1_w  = (const float*)d_in[1];
  const float* ln1_b  = (const float*)d_in[2];
  const float* W_attn = (const float*)d_in[3];
  const float* b_attn = (const float*)d_in[4];
  const float* W_proj = (const float*)d_in[5];
  const float* b_proj = (const float*)d_in[6];
  const float* ln2_w  = (const float*)d_in[7];
  const float* ln2_b  = (const float*)d_in[8];
  const float* W_fc   = (const float*)d_in[9];
  const float* b_fc   = (const float*)d_in[10];
  const float* W_fc2  = (const float*)d_in[11];
  const float* b_fc2  = (const float*)d_in[12];
  float* out = (float*)d_out;

  char* base = (char*)d_ws;
  size_t off = 0;
  auto alloc = [&](size_t bytes) -> void* {
    void* q = base + off;
    off = (off + bytes + 255) & ~(size_t)255;
    return q;
  };
  ushort* Wt_attn = (ushort*)alloc(768ull * 2304 * 2);
  ushort* Wt_proj = (ushort*)alloc(768ull * 768 * 2);
  ushort* Wt_fc   = (ushort*)alloc(768ull * 3072 * 2);
  ushort* Wt_fc2  = (ushort*)alloc(3072ull * 768 * 2);
  ushort* t_ln    = (ushort*)alloc(4096ull * 768 * 2);
  ushort* t_att   = (ushort*)alloc(4096ull * 768 * 2);
  float*  t_x1    = (float*) alloc(4096ull * 768 * 4);
  ushort* t_big   = (ushort*)alloc(4096ull * 3072 * 2);
  ushort* t_qkv = t_big;
  ushort* t_h   = t_big;

  wconv_t<<<dim3(2304 / 32, 768 / 32), 256, 0, stream>>>(W_attn, Wt_attn, 768, 2304);
  wconv_t<<<dim3(768 / 32, 768 / 32), 256, 0, stream>>>(W_proj, Wt_proj, 768, 768);
  wconv_t<<<dim3(3072 / 32, 768 / 32), 256, 0, stream>>>(W_fc, Wt_fc, 768, 3072);
  wconv_t<<<dim3(768 / 32, 3072 / 32), 256, 0, stream>>>(W_fc2, Wt_fc2, 3072, 768);

  ln_kernel<<<4096, 256, 0, stream>>>(x, ln1_w, ln1_b, t_ln);
  gemm_bt<0, 128><<<dim3(2304 / 128, 32), 256, 0, stream>>>(
      t_ln, Wt_attn, b_attn, nullptr, t_qkv, nullptr, 4096, 2304, 768);
  attn_kernel<<<dim3(768), 256, 0, stream>>>(t_qkv, t_att);
  gemm_bt<1, 64><<<dim3(768 / 64, 32), 256, 0, stream>>>(
      t_att, Wt_proj, b_proj, x, nullptr, t_x1, 4096, 768, 768);
  ln_kernel<<<4096, 256, 0, stream>>>(t_x1, ln2_w, ln2_b, t_ln);
  gemm_bt<2, 128><<<dim3(3072 / 128, 32), 256, 0, stream>>>(
      t_ln, Wt_fc, b_fc, nullptr, t_h, nullptr, 4096, 3072, 768);
  gemm_bt<1, 64><<<dim3(768 / 64, 32), 256, 0, stream>>>(
      t_h, Wt_fc2, b_fc2, t_x1, nullptr, out, 4096, 768, 3072);
}

// Round 4
// 202.185 us; speedup vs baseline: 2.4170x; 1.2038x over previous
//
#include <hip/hip_runtime.h>
#include <hip/hip_bf16.h>
#include <math.h>

#define TSEQ 4096
#define CDIM 768
#define NH 12
#define HD 64

typedef float f32x4 __attribute__((ext_vector_type(4)));
typedef __bf16 bf16x8 __attribute__((ext_vector_type(8)));
typedef short s16x8 __attribute__((ext_vector_type(8)));
typedef uint u32x4 __attribute__((ext_vector_type(4)));

__device__ inline ushort f2bf(float f) {
  __hip_bfloat16 h = __float2bfloat16(f);
  return __builtin_bit_cast(ushort, h);
}

__device__ inline void async16(const void* g, void* l) {
  __builtin_amdgcn_global_load_lds(
      (__attribute__((address_space(1))) unsigned int*)(uintptr_t)g,
      (__attribute__((address_space(3))) unsigned int*)(uintptr_t)l, 16, 0, 0);
}

__device__ inline void barrier_all() {
  asm volatile("s_waitcnt vmcnt(0) lgkmcnt(0)" ::: "memory");
  __builtin_amdgcn_sched_barrier(0);
  __builtin_amdgcn_s_barrier();
  __builtin_amdgcn_sched_barrier(0);
}

// v_exp_f32 computes 2^x; s_nop covers the TRANS->VALU hazard
__device__ inline float exp2_fast(float x) {
  float r;
  asm volatile("v_exp_f32 %0, %1\n\ts_nop 0" : "=v"(r) : "v"(x));
  return r;
}

// pack two f32 -> two bf16 in one u32 (lo = a, hi = b)
__device__ inline uint cvtpk(float a, float b) {
  uint r;
  asm volatile("v_cvt_pk_bf16_f32 %0, %1, %2" : "=v"(r) : "v"(a), "v"(b));
  return r;
}

// swizzled fragment read from a [64][64] bf16 tile with row-chunk XOR swizzle
__device__ inline bf16x8 frag_read(const ushort* base, int row, int kk, int lane) {
  const int byte = row * 128 + ((((kk * 4 + (lane >> 4)) ^ (row & 7))) << 4);
  return *(const bf16x8*)((const char*)base + byte);
}

// ---------------- weight transpose fp32 -> bf16, Wt[n][k] = W[k][n] -------
__global__ __launch_bounds__(256) void wconv_t(
    const float* __restrict__ W, ushort* __restrict__ Wt, int K, int N)
{
  __shared__ float sm[32][33];
  const int n0 = blockIdx.x * 32, k0 = blockIdx.y * 32;
  const int c = threadIdx.x & 31, r0 = threadIdx.x >> 5;
#pragma unroll
  for (int i = 0; i < 4; ++i) {
    const int r = r0 + i * 8;
    sm[r][c] = W[(size_t)(k0 + r) * N + n0 + c];
  }
  __syncthreads();
#pragma unroll
  for (int i = 0; i < 4; ++i) {
    const int r = r0 + i * 8;
    Wt[(size_t)(n0 + r) * K + k0 + c] = f2bf(sm[c][r]);
  }
}

// ---------------- layernorm fp32 -> bf16 ---------------------------------
__global__ __launch_bounds__(256) void ln_kernel(
    const float* __restrict__ x, const float* __restrict__ w,
    const float* __restrict__ b, ushort* __restrict__ out)
{
  const int row = blockIdx.x;
  const int tid = threadIdx.x;
  const float* xr = x + (size_t)row * CDIM;
  float v[3];
  float s1 = 0.f, s2 = 0.f;
#pragma unroll
  for (int i = 0; i < 3; ++i) {
    v[i] = xr[tid + i * 256];
    s1 += v[i];
    s2 += v[i] * v[i];
  }
#pragma unroll
  for (int off = 32; off >= 1; off >>= 1) {
    s1 += __shfl_xor(s1, off, 64);
    s2 += __shfl_xor(s2, off, 64);
  }
  __shared__ float red1[4], red2[4];
  if ((tid & 63) == 0) { red1[tid >> 6] = s1; red2[tid >> 6] = s2; }
  __syncthreads();
  s1 = red1[0] + red1[1] + red1[2] + red1[3];
  s2 = red2[0] + red2[1] + red2[2] + red2[3];
  const float mu = s1 * (1.f / CDIM);
  const float var = s2 * (1.f / CDIM) - mu * mu;
  const float inv = rsqrtf(var + 1e-5f);
#pragma unroll
  for (int i = 0; i < 3; ++i) {
    const int c = tid + i * 256;
    out[(size_t)row * CDIM + c] = f2bf((v[i] - mu) * inv * w[c] + b[c]);
  }
}

// ---------------- 128xBN bf16 MFMA GEMM, 2-phase dbuf, C = A@Bt^T + bias --
// EPI 0: bf16 out;  EPI 1: fp32 out = res + v;  EPI 2: bf16 out = gelu(v)
template <int EPI, int BN>
__global__ __launch_bounds__(256) void gemm_bt(
    const ushort* __restrict__ A, const ushort* __restrict__ Bt,
    const float* __restrict__ bias, const float* __restrict__ res,
    ushort* __restrict__ outb, float* __restrict__ outf,
    int M, int N, int K, int gx)
{
  constexpr int NW = BN / 32;   // n-fragments per wave
  __shared__ __align__(16) ushort As[2][128 * 32];
  __shared__ __align__(16) ushort Bs[2][BN * 32];
  const int tid = threadIdx.x;
  const int lane = tid & 63;
  const int wv = tid >> 6;
  // bijective XCD swizzle (nwg % 8 == 0 for all our grids)
  const int nwg = (int)gridDim.x;
  const int bid = (int)blockIdx.x;
  const int sw = (bid & 7) * (nwg >> 3) + (bid >> 3);
  const int rowBase = (sw / gx) * 128;
  const int colBase = (sw % gx) * BN;
  const int wr = (wv >> 1) * 64;
  const int wc = (wv & 1) * (BN / 2);

  f32x4 acc[4][NW] = {};

  const int e0 = tid * 8;
  const int r0 = e0 >> 5, c0 = e0 & 31;
  const int e1 = (tid + 256) * 8;
  const int r1 = e1 >> 5, c1 = e1 & 31;

  const ushort* Ag0 = A + (size_t)(rowBase + r0) * K + c0;
  const ushort* Ag1 = A + (size_t)(rowBase + r1) * K + c1;
  const ushort* Bg0 = Bt + (size_t)(colBase + r0) * K + c0;
  const ushort* Bg1 = Bt + (size_t)(colBase + r1) * K + c1;

  auto stage = [&](int buf, int k0) {
    async16(Ag0 + k0, &As[buf][e0]);
    async16(Ag1 + k0, &As[buf][e1]);
    async16(Bg0 + k0, &Bs[buf][e0]);
    if (BN == 128) async16(Bg1 + k0, &Bs[buf][e1]);
  };

  stage(0, 0);
  int buf = 0;
  for (int k0 = 0; k0 < K; k0 += 32) {
    barrier_all();                      // staged buf ready; buf^1 free
    if (k0 + 32 < K) stage(buf ^ 1, k0 + 32);
    bf16x8 af[4], bfr[NW];
#pragma unroll
    for (int m = 0; m < 4; ++m)
      af[m] = *(const bf16x8*)&As[buf][(wr + m * 16 + (lane & 15)) * 32 + (lane >> 4) * 8];
#pragma unroll
    for (int n = 0; n < NW; ++n)
      bfr[n] = *(const bf16x8*)&Bs[buf][(wc + n * 16 + (lane & 15)) * 32 + (lane >> 4) * 8];
#pragma unroll
    for (int m = 0; m < 4; ++m)
#pragma unroll
      for (int n = 0; n < NW; ++n)
        acc[m][n] = __builtin_amdgcn_mfma_f32_16x16x32_bf16(af[m], bfr[n], acc[m][n], 0, 0, 0);
    buf ^= 1;
  }

#pragma unroll
  for (int n = 0; n < NW; ++n) {
    const int gc = colBase + wc + n * 16 + (lane & 15);
    const float bv = bias[gc];
#pragma unroll
    for (int m = 0; m < 4; ++m) {
#pragma unroll
      for (int j = 0; j < 4; ++j) {
        const int gr = rowBase + wr + m * 16 + (lane >> 4) * 4 + j;
        const float v = acc[m][n][j] + bv;
        if (EPI == 0) {
          outb[(size_t)gr * N + gc] = f2bf(v);
        } else if (EPI == 1) {
          outf[(size_t)gr * N + gc] = res[(size_t)gr * N + gc] + v;
        } else {
          const float g = 0.5f * v * (1.0f + erff(v * 0.70710678118654752f));
          outb[(size_t)gr * N + gc] = f2bf(g);
        }
      }
    }
  }
}

// ---------------- causal flash attention, 64x64 tiles, hd=64 -------------
// Swapped QK^T (q on lane&15, keys on regs) + sigma-permuted V key axis:
// P stays entirely in registers (cvt_pk only, no cross-lane, no LDS P).
__global__ __launch_bounds__(256) void attn_kernel(
    const ushort* __restrict__ qkv, ushort* __restrict__ att)
{
  __shared__ __align__(16) ushort Ks[2][64 * 64];
  __shared__ __align__(16) ushort Vt[2][64 * 64];   // V^T [d][sigma(key)]

  const int tid = threadIdx.x;
  const int lane = tid & 63;
  const int wv = tid >> 6;
  const int g = lane >> 4;
  const int ql = lane & 15;
  // snake remap: CU's resident blocks {p, 511-p, 512+p} -> balanced work
  const int p_ = blockIdx.x & 255, grp = blockIdx.x >> 8;
  const int item = (grp & 1) ? (grp * 256 + 255 - p_) : (grp * 256 + p_);
  const int qb = 63 - (item / 12);
  const int h = item % 12;
  const int t0 = qb * 64;
  const size_t rs = 3 * CDIM;
  const int qo = h * HD, ko = CDIM + h * HD, vo = 2 * CDIM + h * HD;

  const float cexp = 0.18033688f;            // 0.125 * log2(e)
  const float cbias = -32.0f * 0.18033688f;  // fixed max M_raw = 32

  // K staging: pre-swizzled global source -> linear LDS dest
  const int L0 = tid * 16, L1 = (tid + 256) * 16;
  const int r_0 = L0 >> 7, c_0 = ((L0 >> 4) & 7) ^ (r_0 & 7);
  const int r_1 = L1 >> 7, c_1 = ((L1 >> 4) & 7) ^ (r_1 & 7);
  const ushort* kg0 = qkv + (size_t)r_0 * rs + ko + c_0 * 8;
  const ushort* kg1 = qkv + (size_t)r_1 * rs + ko + c_1 * 8;

  // V reg staging: keys (vt, vt+1) x d in [vd, vd+8); sigma-permuted slot
  // sigma(key) = 32*(n>>1) + 8*g + 4*(n&1) + j   (n=key>>4, g=(key>>2)&3, j=key&3)
  const int vt = (tid >> 3) * 2;
  const int vd = (tid & 7) * 8;
  const int slot2 = (32 * ((vt >> 4) >> 1) + 8 * ((vt >> 2) & 3) +
                     4 * ((vt >> 4) & 1) + (vt & 3)) * 2;  // byte offset in row
  const ushort* vg = qkv + (size_t)vt * rs + vo + vd;

  // Q fragments direct from global (bf16, 16B aligned)
  const ushort* qrow = qkv + (size_t)(t0 + wv * 16 + ql) * rs + qo + g * 8;
  const bf16x8 aq0 = *(const bf16x8*)(qrow);
  const bf16x8 aq1 = *(const bf16x8*)(qrow + 32);

  // prologue: V0 regs, K0 -> LDS; then stage V0^T
  s16x8 vA0 = *(const s16x8*)(vg);
  s16x8 vA1 = *(const s16x8*)(vg + rs);
  async16(kg0, (char*)Ks[0] + L0);
  async16(kg1, (char*)Ks[0] + L1);
  asm volatile("s_waitcnt vmcnt(0)" ::: "memory");
#pragma unroll
  for (int jj = 0; jj < 8; ++jj) {
    const int d = vd + jj;
    const uint val = (uint)(ushort)vA0[jj] | ((uint)(ushort)vA1[jj] << 16);
    *(uint*)((char*)Vt[0] + d * 128 + (slot2 ^ (((d >> 1) & 7) << 4))) = val;
  }

  float lsum = 0.f;
  f32x4 accO[4] = {};
  const int swzv = (ql >> 1) & 7;

  auto body = [&](int kb, int cur, bool diag) {
    barrier_all();   // K(kb) staged, V^T(kb) visible

    // prefetch next tile: V regs first (older), then K gload_lds
    s16x8 vN0, vN1;
    const bool pre = (kb < qb);
    if (pre) {
      const size_t koff = (size_t)(kb + 1) * 64 * rs;
      vN0 = *(const s16x8*)(vg + koff);
      vN1 = *(const s16x8*)(vg + koff + rs);
      async16(kg0 + koff, (char*)Ks[cur ^ 1] + L0);
      async16(kg1 + koff, (char*)Ks[cur ^ 1] + L1);
    }

    // QK^T swapped: D[key][q], key = 16n + 4g + j, q = wv*16 + ql
    f32x4 accS[4] = {};
    __builtin_amdgcn_s_setprio(1);
#pragma unroll
    for (int kk = 0; kk < 2; ++kk) {
      const bf16x8 a_q = kk ? aq1 : aq0;
#pragma unroll
      for (int n = 0; n < 4; ++n)
        accS[n] = __builtin_amdgcn_mfma_f32_16x16x32_bf16(
            frag_read(Ks[cur], n * 16 + ql, kk, lane), a_q, accS[n], 0, 0, 0);
    }
    __builtin_amdgcn_s_setprio(0);

    // p = 2^(s*c + cbias), diag mask, row-sum, pack to A-fragments in-reg
    uint pk[8];
#pragma unroll
    for (int n = 0; n < 4; ++n) {
      float pv[4];
#pragma unroll
      for (int j = 0; j < 4; ++j) {
        float s = exp2_fast(fmaf(accS[n][j], cexp, cbias));
        if (diag && (kb * 64 + 16 * n + 4 * g + j) > (t0 + wv * 16 + ql)) s = 0.f;
        pv[j] = s;
        lsum += s;
      }
      pk[2 * n] = cvtpk(pv[0], pv[1]);
      pk[2 * n + 1] = cvtpk(pv[2], pv[3]);
    }
    const bf16x8 pf0 = __builtin_bit_cast(bf16x8, (u32x4){pk[0], pk[1], pk[2], pk[3]});
    const bf16x8 pf1 = __builtin_bit_cast(bf16x8, (u32x4){pk[4], pk[5], pk[6], pk[7]});

    // PV: D[q][d]; A = in-reg P (rows=q), B = Vt rows (d), k-dim = sigma slots
    __builtin_amdgcn_s_setprio(1);
#pragma unroll
    for (int kk = 0; kk < 2; ++kk) {
      const bf16x8 a_p = kk ? pf1 : pf0;
#pragma unroll
      for (int n = 0; n < 4; ++n) {
        const int byte = (n * 16 + ql) * 128 + ((kk * 64 + g * 16) ^ (swzv << 4));
        const bf16x8 bv = *(const bf16x8*)((const char*)Vt[cur] + byte);
        accO[n] = __builtin_amdgcn_mfma_f32_16x16x32_bf16(a_p, bv, accO[n], 0, 0, 0);
      }
    }
    __builtin_amdgcn_s_setprio(0);

    // stage V^T(kb+1) (visible after next barrier)
    if (pre) {
#pragma unroll
      for (int jj = 0; jj < 8; ++jj) {
        const int d = vd + jj;
        const uint val = (uint)(ushort)vN0[jj] | ((uint)(ushort)vN1[jj] << 16);
        *(uint*)((char*)Vt[cur ^ 1] + d * 128 + (slot2 ^ (((d >> 1) & 7) << 4))) = val;
      }
    }
  };

  int cur = 0;
  for (int kb = 0; kb < qb; ++kb) {
    body(kb, cur, false);
    cur ^= 1;
  }
  body(qb, cur, true);

  // l[q]: sum partial rows over the 4 lane-groups
  lsum += __shfl_xor(lsum, 16, 64);
  lsum += __shfl_xor(lsum, 32, 64);
  // accO[n][jr]: q_tile = 4g + jr, d = 16n + ql; fetch l for q_tile
  float inv[4];
#pragma unroll
  for (int jr = 0; jr < 4; ++jr)
    inv[jr] = 1.0f / __shfl(lsum, 4 * g + jr, 64);
#pragma unroll
  for (int n = 0; n < 4; ++n)
#pragma unroll
    for (int jr = 0; jr < 4; ++jr) {
      const int tq = t0 + wv * 16 + 4 * g + jr;
      const int d = n * 16 + ql;
      att[(size_t)tq * CDIM + h * HD + d] = f2bf(accO[n][jr] * inv[jr]);
    }
}

// -------------------------------------------------------------------------
extern "C" void kernel_launch(void* const* d_in, const int* in_sizes, int n_in,
                              void* d_out, int out_size, void* d_ws, size_t ws_size,
                              hipStream_t stream)
{
  const float* x      = (const float*)d_in[0];
  const float* ln1_w  = (const float*)d_in[1];
  const float* ln1_b  = (const float*)d_in[2];
  const float* W_attn = (const float*)d_in[3];
  const float* b_attn = (const float*)d_in[4];
  const float* W_proj = (const float*)d_in[5];
  const float* b_proj = (const float*)d_in[6];
  const float* ln2_w  = (const float*)d_in[7];
  const float* ln2_b  = (const float*)d_in[8];
  const float* W_fc   = (const float*)d_in[9];
  const float* b_fc   = (const float*)d_in[10];
  const float* W_fc2  = (const float*)d_in[11];
  const float* b_fc2  = (const float*)d_in[12];
  float* out = (float*)d_out;

  char* base = (char*)d_ws;
  size_t off = 0;
  auto alloc = [&](size_t bytes) -> void* {
    void* q = base + off;
    off = (off + bytes + 255) & ~(size_t)255;
    return q;
  };
  ushort* Wt_attn = (ushort*)alloc(768ull * 2304 * 2);
  ushort* Wt_proj = (ushort*)alloc(768ull * 768 * 2);
  ushort* Wt_fc   = (ushort*)alloc(768ull * 3072 * 2);
  ushort* Wt_fc2  = (ushort*)alloc(3072ull * 768 * 2);
  ushort* t_ln    = (ushort*)alloc(4096ull * 768 * 2);
  ushort* t_att   = (ushort*)alloc(4096ull * 768 * 2);
  float*  t_x1    = (float*) alloc(4096ull * 768 * 4);
  ushort* t_big   = (ushort*)alloc(4096ull * 3072 * 2);
  ushort* t_qkv = t_big;
  ushort* t_h   = t_big;

  wconv_t<<<dim3(2304 / 32, 768 / 32), 256, 0, stream>>>(W_attn, Wt_attn, 768, 2304);
  wconv_t<<<dim3(768 / 32, 768 / 32), 256, 0, stream>>>(W_proj, Wt_proj, 768, 768);
  wconv_t<<<dim3(3072 / 32, 768 / 32), 256, 0, stream>>>(W_fc, Wt_fc, 768, 3072);
  wconv_t<<<dim3(768 / 32, 3072 / 32), 256, 0, stream>>>(W_fc2, Wt_fc2, 3072, 768);

  ln_kernel<<<4096, 256, 0, stream>>>(x, ln1_w, ln1_b, t_ln);
  gemm_bt<0, 128><<<18 * 32, 256, 0, stream>>>(
      t_ln, Wt_attn, b_attn, nullptr, t_qkv, nullptr, 4096, 2304, 768, 18);
  attn_kernel<<<dim3(768), 256, 0, stream>>>(t_qkv, t_att);
  gemm_bt<1, 64><<<12 * 32, 256, 0, stream>>>(
      t_att, Wt_proj, b_proj, x, nullptr, t_x1, 4096, 768, 768, 12);
  ln_kernel<<<4096, 256, 0, stream>>>(t_x1, ln2_w, ln2_b, t_ln);
  gemm_bt<2, 128><<<24 * 32, 256, 0, stream>>>(
      t_ln, Wt_fc, b_fc, nullptr, t_h, nullptr, 4096, 3072, 768, 24);
  gemm_bt<1, 64><<<12 * 32, 256, 0, stream>>>(
      t_h, Wt_fc2, b_fc2, t_x1, nullptr, out, 4096, 768, 3072, 12);
}